// Round 14
// baseline (160.909 us; speedup 1.0000x reference)
//
#include <hip/hip_runtime.h>
#include <math.h>

#define B_N 2048
#define D_FT 784
#define K_N 50
#define L_N 6
#define LOG2PI_F 1.8378770664093453f

// ---- output layout (floats), concatenated in reference return order ----
#define OUT_PW 0
#define OUT_M  (B_N)                              // 2048
#define OUT_A  (OUT_M + B_N*D_FT)                 // 1607680
#define OUT_D  (OUT_A + B_N*D_FT*6)               // 11241472

// ---- workspace layout (float offsets) ----
#define WS_SCORES 0                                // [K][B]     102400
#define WS_PQ     (WS_SCORES + K_N*B_N)            // [K][27][B] 2764800
#define WS_XT     (WS_PQ + K_N*27*B_N)             // [D/4][B]   1605632
#define WS_JBT    (WS_XT + D_FT*B_N)               // [25][B]    51200
#define WS_WREC   (WS_JBT + 25*B_N)                // [K][784][8] 313600 (16-aligned)
#define WS_WLD    (WS_WREC + K_N*D_FT*8)           // [K][784]    39200

#define IDX(i,j) ((i)*((i)+1)/2 + (j))   // packed lower, i>=j

// Constant address space: uniform loads from AS(4) compile to s_load_* via the
// scalar cache -> record data lives in SGPRs, costs ZERO LDS and ZERO VGPR.
// (r7 showed plain global loads do NOT auto-scalarize; r12/r13 showed the LDS
// return path at ~55 us is the largest pipe demand. This removes it.)
#define CAS const __attribute__((address_space(4)))

// ---------- 6x6 packed-lower Cholesky ----------
__device__ __forceinline__ void chol6(const float* P, float* L, float* rd, float* sumlog) {
    float sl = 0.f;
    #pragma unroll
    for (int j = 0; j < 6; ++j) {
        float s = P[IDX(j,j)];
        #pragma unroll
        for (int m = 0; m < j; ++m) s -= L[IDX(j,m)] * L[IDX(j,m)];
        float d = sqrtf(s);
        L[IDX(j,j)] = d;
        float r = 1.0f / d;
        rd[j] = r;
        sl += logf(d);
        #pragma unroll
        for (int i = j + 1; i < 6; ++i) {
            float t = P[IDX(i,j)];
            #pragma unroll
            for (int m = 0; m < j; ++m) t -= L[IDX(i,m)] * L[IDX(j,m)];
            L[IDX(i,j)] = t * r;
        }
    }
    *sumlog = sl;
}

// ---------- K0: transpose + packbits + record build, one kernel ----------
// blocks 0..447: X transpose tiles; 448..511: packbits; 512..561: records.
__global__ __launch_bounds__(1024) void k_prep(const float* __restrict__ X,
                                               const int* __restrict__ J,
                                               const float* __restrict__ A,
                                               const float* __restrict__ MU,
                                               const float* __restrict__ logD,
                                               float4* __restrict__ Xt4,
                                               unsigned* __restrict__ JbT,
                                               float* __restrict__ Wrec,
                                               float* __restrict__ Wld) {
    const int bid = blockIdx.x;
    const int tid = threadIdx.x;
    if (bid < 448) {
        __shared__ float4 tile[32][33];
        int tx = tid & 31, ty = tid >> 5;
        int d4b = (bid % 7) * 32;
        int bb  = (bid / 7) * 32;
        int d4 = d4b + tx;
        if (d4 < D_FT / 4)
            tile[ty][tx] = *(const float4*)&X[(size_t)(bb + ty) * D_FT + d4 * 4];
        __syncthreads();
        int d4o = d4b + ty;
        if (d4o < D_FT / 4)
            Xt4[(size_t)d4o * B_N + (bb + tx)] = tile[tx][ty];
    } else if (bid < 512) {
        int t = (bid - 448) * 1024 + tid;    // 65536 threads = 2048 b x 32 w
        int b = t >> 5;
        int w = t & 31;
        if (w >= 25) return;
        int d0 = w * 32;
        int n = D_FT - d0; if (n > 32) n = 32;
        unsigned u = 0;
        for (int j = 0; j < n; ++j)
            u |= (J[(size_t)b * D_FT + d0 + j] != 0 ? 1u : 0u) << j;
        JbT[(size_t)w * B_N + b] = u;
    } else {
        const int k = bid - 512;
        for (int d = tid; d < D_FT; d += 1024) {
            const float* ar = A + ((size_t)k * D_FT + d) * 6;
            float ld = logD[(size_t)k * D_FT + d];
            float4 r0, r1;
            r0.x = ar[0]; r0.y = ar[1]; r0.z = ar[2]; r0.w = ar[3];
            r1.x = ar[4]; r1.y = ar[5];
            r1.z = expf(-ld);
            r1.w = -MU[(size_t)k * D_FT + d];
            float4* wr = (float4*)(Wrec + ((size_t)k * D_FT + d) * 8);
            wr[0] = r0; wr[1] = r1;
            Wld[(size_t)k * D_FT + d] = ld;
        }
    }
}

// ---------- K1: per-(sample,k) accumulation + loglik ----------
// 256 threads = 64 samples x 4 d-quarters. Records read via AS(4) scalar
// loads (s_load through K$) -> NO LDS staging, NO staging barriers, LDS is
// only the 8.4 KB merge slab. Math: plain scalar f32 (same VALU cycle rate
// as v_pk: 1 fma/2cyc == 2/4cyc), 29 f32 accumulators -> low VGPR.
// Math (== r10, proven absmax): wgt = m*invD; z = x-mu; t = wgt*z;
//   P_ij += (wgt*a_i)*a_j; q_j += t*a_j; quad += t*z; jld += m*logD.
// launch_bounds(256,3): allocator accepts >64 VGPR without spilling (r11);
// (256,4) pins at 64 and spills extras (r9); min-waves>=6 catastrophic (r3/r4).
#define ACC_D(di, dd, xval) do { \
    const size_t ro = (size_t)(di) * 8; \
    const float a0 = Wr[ro + 0], a1 = Wr[ro + 1], a2 = Wr[ro + 2]; \
    const float a3 = Wr[ro + 3], a4 = Wr[ro + 4], a5 = Wr[ro + 5]; \
    const float iD = Wr[ro + 6], nmu = Wr[ro + 7]; \
    const float ldv = Wl[(di)]; \
    const float m = (float)((mw >> (dd)) & 1u); \
    const float wgt = m * iD; \
    const float z = (xval) + nmu; \
    const float t = wgt * z; \
    quad = fmaf(t, z, quad); \
    jld  = fmaf(m, ldv, jld); \
    const float u0 = wgt*a0, u1 = wgt*a1, u2 = wgt*a2; \
    const float u3 = wgt*a3, u4 = wgt*a4, u5 = wgt*a5; \
    Pm[0]  = fmaf(u0, a0, Pm[0]); \
    Pm[1]  = fmaf(u1, a0, Pm[1]);  Pm[2]  = fmaf(u1, a1, Pm[2]); \
    Pm[3]  = fmaf(u2, a0, Pm[3]);  Pm[4]  = fmaf(u2, a1, Pm[4]);  Pm[5]  = fmaf(u2, a2, Pm[5]); \
    Pm[6]  = fmaf(u3, a0, Pm[6]);  Pm[7]  = fmaf(u3, a1, Pm[7]);  Pm[8]  = fmaf(u3, a2, Pm[8]);  Pm[9]  = fmaf(u3, a3, Pm[9]); \
    Pm[10] = fmaf(u4, a0, Pm[10]); Pm[11] = fmaf(u4, a1, Pm[11]); Pm[12] = fmaf(u4, a2, Pm[12]); Pm[13] = fmaf(u4, a3, Pm[13]); Pm[14] = fmaf(u4, a4, Pm[14]); \
    Pm[15] = fmaf(u5, a0, Pm[15]); Pm[16] = fmaf(u5, a1, Pm[16]); Pm[17] = fmaf(u5, a2, Pm[17]); Pm[18] = fmaf(u5, a3, Pm[18]); Pm[19] = fmaf(u5, a4, Pm[19]); Pm[20] = fmaf(u5, a5, Pm[20]); \
    qv[0] = fmaf(t, a0, qv[0]); qv[1] = fmaf(t, a1, qv[1]); qv[2] = fmaf(t, a2, qv[2]); \
    qv[3] = fmaf(t, a3, qv[3]); qv[4] = fmaf(t, a4, qv[4]); qv[5] = fmaf(t, a5, qv[5]); \
} while (0)

__global__ __launch_bounds__(256, 3) void k_accum(
        const float4* __restrict__ Xt4, const unsigned* __restrict__ JbT,
        const float* __restrict__ WrecG, const float* __restrict__ WldG,
        const float* __restrict__ PI,
        float* __restrict__ scores, float* __restrict__ Pq) {
    __shared__ float red[64 * 33];      // 8448 B merge slab (only LDS use)
    const int k   = blockIdx.x >> 5;
    const int tid = threadIdx.x;
    const int s   = tid & 63;
    const int h   = tid >> 6;           // d-quarter 0..3
    const int b   = (blockIdx.x & 31) * 64 + s;

    CAS float* Wr = (CAS float*)(uintptr_t)(WrecG + (size_t)k * D_FT * 8);
    CAS float* Wl = (CAS float*)(uintptr_t)(WldG + (size_t)k * D_FT);

    float Pm[21], qv[6];
    #pragma unroll
    for (int t = 0; t < 21; ++t) Pm[t] = 0.f;
    #pragma unroll
    for (int t = 0; t < 6; ++t) qv[t] = 0.f;
    float quad = 0.f, jld = 0.f;
    int nob = 0;

    const int w0 = 6 * h;
    const int w1 = (h == 3) ? 24 : (6 * h + 6);
    for (int w = w0; w < w1; ++w) {
        const unsigned mw = JbT[(size_t)w * B_N + b];
        nob += __popc(mw);
        const int dwb = w * 32;
        const float4* xp = Xt4 + (size_t)(w * 8) * B_N + b;
        #pragma unroll 4
        for (int g = 0; g < 8; ++g) {
            float4 xv = xp[(size_t)g * B_N];
            ACC_D(dwb + 4 * g + 0, 4 * g + 0, xv.x);
            ACC_D(dwb + 4 * g + 1, 4 * g + 1, xv.y);
            ACC_D(dwb + 4 * g + 2, 4 * g + 2, xv.z);
            ACC_D(dwb + 4 * g + 3, 4 * g + 3, xv.w);
        }
    }
    if (h == 3) {  // tail word 24: bits 0..15 valid (d 768..783)
        const unsigned mw = JbT[(size_t)24 * B_N + b];
        nob += __popc(mw);
        const int dwb = 768;
        const float4* xp = Xt4 + (size_t)(24 * 8) * B_N + b;
        #pragma unroll
        for (int g = 0; g < 4; ++g) {
            float4 xv = xp[(size_t)g * B_N];
            ACC_D(dwb + 4 * g + 0, 4 * g + 0, xv.x);
            ACC_D(dwb + 4 * g + 1, 4 * g + 1, xv.y);
            ACC_D(dwb + 4 * g + 2, 4 * g + 2, xv.z);
            ACC_D(dwb + 4 * g + 3, 4 * g + 3, xv.w);
        }
    }

    // 4-quarter merge through one 64x33 slab (conflict-free, 33 % 32 == 1).
    #define SLAB_WR do { float* o = &red[s * 33]; \
        _Pragma("unroll") for (int t = 0; t < 21; ++t) o[t] = Pm[t]; \
        _Pragma("unroll") for (int t = 0; t < 6; ++t) o[21 + t] = qv[t]; \
        o[27] = quad; o[28] = (float)nob; o[29] = jld; } while (0)
    #define SLAB_ADD do { const float* o = &red[s * 33]; \
        _Pragma("unroll") for (int t = 0; t < 21; ++t) Pm[t] += o[t]; \
        _Pragma("unroll") for (int t = 0; t < 6; ++t) qv[t] += o[21 + t]; \
        quad += o[27]; nob += (int)o[28]; jld += o[29]; } while (0)

    if (h == 1) SLAB_WR;
    __syncthreads();
    if (h == 0) SLAB_ADD;
    __syncthreads();
    if (h == 3) SLAB_WR;
    __syncthreads();
    if (h == 2) SLAB_ADD;
    __syncthreads();
    if (h == 2) SLAB_WR;
    __syncthreads();
    if (h == 0) {
        SLAB_ADD;
        float nobs = (float)nob;

        // P = I + sum
        Pm[0] += 1.f; Pm[2] += 1.f; Pm[5] += 1.f; Pm[9] += 1.f; Pm[14] += 1.f; Pm[20] += 1.f;

        float Lm[21], rd[6], sumlog;
        chol6(Pm, Lm, rd, &sumlog);
        float y[6];
        #pragma unroll
        for (int j = 0; j < 6; ++j) {
            float sv = qv[j];
            #pragma unroll
            for (int m = 0; m < j; ++m) sv -= Lm[IDX(j,m)] * y[m];
            y[j] = sv * rd[j];
        }
        float yy = 0.f;
        #pragma unroll
        for (int j = 0; j < 6; ++j) yy += y[j] * y[j];
        float logdet = 2.f * sumlog + jld;
        float ll = -0.5f * ((quad - yy) + logdet + nobs * LOG2PI_F);
        float score = ll + PI[k];

        scores[(size_t)k * B_N + b] = score;
        float* pq = Pq + (size_t)k * 27 * B_N + b;
        #pragma unroll
        for (int t = 0; t < 21; ++t) pq[(size_t)t * B_N] = Pm[t];
        #pragma unroll
        for (int t = 0; t < 6; ++t) pq[(size_t)(21 + t) * B_N] = qv[t];
    }
}

// ---------- KD: fused argmax + latent solve (wave 0 only) + output write ----------
__global__ __launch_bounds__(256) void k_outsel(
        const float* __restrict__ scores, const float* __restrict__ Pq,
        const float* __restrict__ A, const float* __restrict__ MU,
        const float* __restrict__ logD, float* __restrict__ out) {
    __shared__ float smz[6];
    __shared__ float sLz[21];
    __shared__ int sc;
    const int b = blockIdx.x;
    const int tid = threadIdx.x;

    if (tid < 64) {
        float best = scores[b];
        int bc = 0;
        for (int kk = 1; kk < K_N; ++kk) {
            float sv = scores[(size_t)kk * B_N + b];
            if (sv > best) { best = sv; bc = kk; }
        }

        float Pm[21], qv[6];
        const float* pq = Pq + (size_t)bc * 27 * B_N + b;
        #pragma unroll
        for (int t = 0; t < 21; ++t) Pm[t] = pq[(size_t)t * B_N];
        #pragma unroll
        for (int t = 0; t < 6; ++t) qv[t] = pq[(size_t)(21 + t) * B_N];

        float Lm[21], rd[6], dummy;
        chol6(Pm, Lm, rd, &dummy);

        float y[6];
        #pragma unroll
        for (int j = 0; j < 6; ++j) {
            float sv = qv[j];
            #pragma unroll
            for (int m = 0; m < j; ++m) sv -= Lm[IDX(j,m)] * y[m];
            y[j] = sv * rd[j];
        }
        float mz[6];
        #pragma unroll
        for (int ii = 5; ii >= 0; --ii) {
            float sv = y[ii];
            #pragma unroll
            for (int j = ii + 1; j < 6; ++j) sv -= Lm[IDX(j,ii)] * mz[j];
            mz[ii] = sv * rd[ii];
        }
        float Li[21];
        #pragma unroll
        for (int j = 0; j < 6; ++j) {
            Li[IDX(j,j)] = rd[j];
            #pragma unroll
            for (int i = j + 1; i < 6; ++i) {
                float sv = 0.f;
                #pragma unroll
                for (int m = j; m < i; ++m) sv += Lm[IDX(i,m)] * Li[IDX(m,j)];
                Li[IDX(i,j)] = -sv * rd[i];
            }
        }
        float cov[21];
        #pragma unroll
        for (int i = 0; i < 6; ++i) {
            #pragma unroll
            for (int j = 0; j <= i; ++j) {
                float sv = 0.f;
                #pragma unroll
                for (int m = i; m < 6; ++m) sv += Li[IDX(m,i)] * Li[IDX(m,j)];
                cov[IDX(i,j)] = sv;
            }
        }
        float Lz[21], rd2[6];
        chol6(cov, Lz, rd2, &dummy);

        if (tid == 0) {
            sc = bc;
            out[OUT_PW + b] = 1.0f;
            #pragma unroll
            for (int t = 0; t < 6; ++t) smz[t] = mz[t];
            #pragma unroll
            for (int t = 0; t < 21; ++t) sLz[t] = Lz[t];
        }
    }
    __syncthreads();
    const int c = sc;

    for (int d = tid; d < D_FT; d += 256) {
        const float* ar = A + ((size_t)c * D_FT + d) * 6;
        float a[6];
        #pragma unroll
        for (int i = 0; i < 6; ++i) a[i] = ar[i];
        float mu = MU[(size_t)c * D_FT + d];
        float ld = logD[(size_t)c * D_FT + d];
        float m = mu;
        #pragma unroll
        for (int i = 0; i < 6; ++i) m += a[i] * smz[i];
        out[OUT_M + (size_t)b * D_FT + d] = m;
        out[OUT_D + (size_t)b * D_FT + d] = expf(ld);
        float* ao = out + OUT_A + ((size_t)b * D_FT + d) * 6;
        #pragma unroll
        for (int j = 0; j < 6; ++j) {
            float sv = 0.f;
            #pragma unroll
            for (int i = j; i < 6; ++i) sv += a[i] * sLz[IDX(i,j)];
            ao[j] = sv;
        }
    }
}

extern "C" void kernel_launch(void* const* d_in, const int* in_sizes, int n_in,
                              void* d_out, int out_size, void* d_ws, size_t ws_size,
                              hipStream_t stream) {
    (void)in_sizes; (void)n_in; (void)out_size; (void)ws_size;
    const float* X    = (const float*)d_in[0];
    const int*   J    = (const int*)d_in[1];
    const float* MU   = (const float*)d_in[2];
    const float* A    = (const float*)d_in[3];
    const float* logD = (const float*)d_in[4];
    const float* PI   = (const float*)d_in[5];
    float* out = (float*)d_out;
    float* ws  = (float*)d_ws;

    float*    scores = ws + WS_SCORES;
    float*    Pq     = ws + WS_PQ;
    float4*   Xt4    = (float4*)(ws + WS_XT);
    unsigned* JbT    = (unsigned*)(ws + WS_JBT);
    float*    Wrec   = ws + WS_WREC;
    float*    Wld    = ws + WS_WLD;

    k_prep<<<562, 1024, 0, stream>>>(X, J, A, MU, logD, Xt4, JbT, Wrec, Wld);

    k_accum<<<32 * K_N, 256, 0, stream>>>(Xt4, JbT, Wrec, Wld, PI, scores, Pq);

    k_outsel<<<B_N, 256, 0, stream>>>(scores, Pq, A, MU, logD, out);
}

// Round 15
// 115.942 us; speedup vs baseline: 1.3878x; 1.3878x over previous
//
#include <hip/hip_runtime.h>
#include <math.h>

#define B_N 2048
#define D_FT 784
#define K_N 50
#define L_N 6
#define LOG2PI_F 1.8378770664093453f

// ---- output layout (floats), concatenated in reference return order ----
#define OUT_PW 0
#define OUT_M  (B_N)                              // 2048
#define OUT_A  (OUT_M + B_N*D_FT)                 // 1607680
#define OUT_D  (OUT_A + B_N*D_FT*6)               // 11241472

// ---- workspace layout (float offsets) ----
#define WS_SCORES 0                                // [K][B]
#define WS_PQ     (WS_SCORES + K_N*B_N)            // [K][27][B] 2764800
#define WS_XT     (WS_PQ + K_N*27*B_N)             // [D/4][B] float4 = D*B floats
#define WS_JBT    (WS_XT + D_FT*B_N)               // [25][B]    51200

#define IDX(i,j) ((i)*((i)+1)/2 + (j))   // packed lower, i>=j

typedef float v2f __attribute__((ext_vector_type(2)));

// ALL packed math as explicit VOP3P asm (r12 body — best known: 89.7 us).
#define PK_FMA(acc, a, b) asm("v_pk_fma_f32 %0, %1, %2, %0" : "+v"(acc) : "v"(a), "v"(b))
#define PK_MUL(dst, a, b) asm("v_pk_mul_f32 %0, %1, %2" : "=v"(dst) : "v"(a), "v"(b))
#define PK_ADD(dst, a, b) asm("v_pk_add_f32 %0, %1, %2" : "=v"(dst) : "v"(a), "v"(b))

// ---------- 6x6 packed-lower Cholesky ----------
__device__ __forceinline__ void chol6(const float* P, float* L, float* rd, float* sumlog) {
    float sl = 0.f;
    #pragma unroll
    for (int j = 0; j < 6; ++j) {
        float s = P[IDX(j,j)];
        #pragma unroll
        for (int m = 0; m < j; ++m) s -= L[IDX(j,m)] * L[IDX(j,m)];
        float d = sqrtf(s);
        L[IDX(j,j)] = d;
        float r = 1.0f / d;
        rd[j] = r;
        sl += logf(d);
        #pragma unroll
        for (int i = j + 1; i < 6; ++i) {
            float t = P[IDX(i,j)];
            #pragma unroll
            for (int m = 0; m < j; ++m) t -= L[IDX(i,m)] * L[IDX(j,m)];
            L[IDX(i,j)] = t * r;
        }
    }
    *sumlog = sl;
}

// ---------- K0: fused transpose (X -> Xt4) + packbits (J -> JbT) ----------
__global__ __launch_bounds__(1024) void k_prep(const float* __restrict__ X,
                                               const int* __restrict__ J,
                                               float4* __restrict__ Xt4,
                                               unsigned* __restrict__ JbT) {
    const int bid = blockIdx.x;
    const int tid = threadIdx.x;
    if (bid < 448) {
        __shared__ float4 tile[32][33];
        int tx = tid & 31, ty = tid >> 5;
        int d4b = (bid % 7) * 32;
        int bb  = (bid / 7) * 32;
        int d4 = d4b + tx;
        if (d4 < D_FT / 4)
            tile[ty][tx] = *(const float4*)&X[(size_t)(bb + ty) * D_FT + d4 * 4];
        __syncthreads();
        int d4o = d4b + ty;
        if (d4o < D_FT / 4)
            Xt4[(size_t)d4o * B_N + (bb + tx)] = tile[tx][ty];
    } else {
        int t = (bid - 448) * 1024 + tid;    // 65536 threads = 2048 b x 32 w
        int b = t >> 5;
        int w = t & 31;
        if (w >= 25) return;
        int d0 = w * 32;
        int n = D_FT - d0; if (n > 32) n = 32;
        unsigned u = 0;
        for (int j = 0; j < n; ++j)
            u |= (J[(size_t)b * D_FT + d0 + j] != 0 ? 1u : 0u) << j;
        JbT[(size_t)w * B_N + b] = u;
    }
}

// ---------- K1: per-(sample,k) accumulation + loglik (r12 body, proven) ----------
// 256 threads = 64 samples x 4 d-quarters; d staged in two chunks.
// Record = 10 v2f slots / pair (80 B): a~0..a~5 pairs, sa pair, -mu pair,
// logD pair, pad. Reads are wave-uniform ds_read_b64 -> broadcast into
// even-aligned VGPR pairs (asm-ready).
// Math (m^2=m): u_i = m*a~_i; P_ij += u_i*a~_j; z = (m*sa)*(x-mu);
//   q_j += z*a~_j; quad += z*z; jld += m*logD.  (a~ = sa*a, sa = exp(-ld/2))
// LEDGER (do not re-try): records in global VMEM +24us (r7); AS(4) scalar
// s_load +57us serialization (r14); 2-sample/thread spills (r13); x-hoist
// spills at any bound (r9/r11); min-waves>=6 catastrophic spill (r3/r4);
// (256,4) pins allocator at 64 VGPR (r9); (256,3) accepts ~80-84 max (r11/r13).
// Dual-pipe bound: VALU issue ~45-53us || LDS return ~50us -> ~90us floor.
#define ACC_PAIR(pi, dd, x0, x1) do { \
    const v2f a0 = sld[(size_t)(pi) * 10 + 0]; \
    const v2f a1 = sld[(size_t)(pi) * 10 + 1]; \
    const v2f a2 = sld[(size_t)(pi) * 10 + 2]; \
    const v2f a3 = sld[(size_t)(pi) * 10 + 3]; \
    const v2f a4 = sld[(size_t)(pi) * 10 + 4]; \
    const v2f a5 = sld[(size_t)(pi) * 10 + 5]; \
    const v2f sa2  = sld[(size_t)(pi) * 10 + 6]; \
    const v2f nmu2 = sld[(size_t)(pi) * 10 + 7]; \
    const v2f l2   = sld[(size_t)(pi) * 10 + 8]; \
    v2f m2; m2.x = (float)((mw >> (dd)) & 1u); m2.y = (float)((mw >> ((dd)+1)) & 1u); \
    v2f x2; x2.x = (x0); x2.y = (x1); \
    v2f xm2; PK_ADD(xm2, x2, nmu2); \
    v2f w2;  PK_MUL(w2, m2, sa2); \
    v2f z2;  PK_MUL(z2, w2, xm2); \
    v2f u0, u1, u2v, u3, u4, u5; \
    PK_MUL(u0, m2, a0); PK_MUL(u1, m2, a1); PK_MUL(u2v, m2, a2); \
    PK_MUL(u3, m2, a3); PK_MUL(u4, m2, a4); PK_MUL(u5, m2, a5); \
    PK_FMA(jld2, m2, l2); \
    PK_FMA(Pm2[0],  u0, a0); \
    PK_FMA(Pm2[1],  u1, a0); PK_FMA(Pm2[2],  u1, a1); \
    PK_FMA(Pm2[3],  u2v, a0); PK_FMA(Pm2[4],  u2v, a1); PK_FMA(Pm2[5],  u2v, a2); \
    PK_FMA(Pm2[6],  u3, a0); PK_FMA(Pm2[7],  u3, a1); PK_FMA(Pm2[8],  u3, a2); PK_FMA(Pm2[9],  u3, a3); \
    PK_FMA(Pm2[10], u4, a0); PK_FMA(Pm2[11], u4, a1); PK_FMA(Pm2[12], u4, a2); PK_FMA(Pm2[13], u4, a3); PK_FMA(Pm2[14], u4, a4); \
    PK_FMA(Pm2[15], u5, a0); PK_FMA(Pm2[16], u5, a1); PK_FMA(Pm2[17], u5, a2); PK_FMA(Pm2[18], u5, a3); PK_FMA(Pm2[19], u5, a4); PK_FMA(Pm2[20], u5, a5); \
    PK_FMA(qv2[0], z2, a0); PK_FMA(qv2[1], z2, a1); PK_FMA(qv2[2], z2, a2); \
    PK_FMA(qv2[3], z2, a3); PK_FMA(qv2[4], z2, a4); PK_FMA(qv2[5], z2, a5); \
    PK_FMA(quad2, z2, z2); \
} while (0)

__global__ __launch_bounds__(256, 3) void k_accum(
        const float4* __restrict__ Xt4, const unsigned* __restrict__ JbT,
        const float* __restrict__ A, const float* __restrict__ MU,
        const float* __restrict__ logD, const float* __restrict__ PI,
        float* __restrict__ scores, float* __restrict__ Pq) {
    __shared__ v2f sld[200 * 10];       // 16000 B records; aliased as merge slab
    float* smem = (float*)sld;
    float4* smf4 = (float4*)sld;
    const int k   = blockIdx.x >> 5;
    const int tid = threadIdx.x;
    const int s   = tid & 63;
    const int h   = tid >> 6;           // d-quarter 0..3
    const int b   = (blockIdx.x & 31) * 64 + s;

    v2f Pm2[21], qv2[6], quad2, jld2;
    #pragma unroll
    for (int t = 0; t < 21; ++t) { Pm2[t].x = 0.f; Pm2[t].y = 0.f; }
    #pragma unroll
    for (int t = 0; t < 6; ++t) { qv2[t].x = 0.f; qv2[t].y = 0.f; }
    quad2.x = 0.f; quad2.y = 0.f;
    jld2.x = 0.f; jld2.y = 0.f;
    int nob = 0;

    for (int c = 0; c < 2; ++c) {
        const int dbase = c ? 384 : 0;
        const int npair = c ? 200 : 192;
        __syncthreads();                 // all quarters done reading old records
        for (int p = tid; p < npair; p += 256) {
            const int d0 = dbase + 2 * p;
            const float* ar0 = A + ((size_t)k * D_FT + d0) * 6;
            const float* ar1 = ar0 + 6;
            float ld0 = logD[(size_t)k * D_FT + d0];
            float ld1 = logD[(size_t)k * D_FT + d0 + 1];
            float sa0 = expf(-0.5f * ld0);
            float sa1 = expf(-0.5f * ld1);
            float4 f0, f1, f2, f3, f4;
            f0.x = sa0 * ar0[0]; f0.y = sa1 * ar1[0]; f0.z = sa0 * ar0[1]; f0.w = sa1 * ar1[1];
            f1.x = sa0 * ar0[2]; f1.y = sa1 * ar1[2]; f1.z = sa0 * ar0[3]; f1.w = sa1 * ar1[3];
            f2.x = sa0 * ar0[4]; f2.y = sa1 * ar1[4]; f2.z = sa0 * ar0[5]; f2.w = sa1 * ar1[5];
            f3.x = sa0; f3.y = sa1;
            f3.z = -MU[(size_t)k * D_FT + d0];
            f3.w = -MU[(size_t)k * D_FT + d0 + 1];
            f4.x = ld0; f4.y = ld1; f4.z = 0.f; f4.w = 0.f;
            smf4[(size_t)p * 5 + 0] = f0;
            smf4[(size_t)p * 5 + 1] = f1;
            smf4[(size_t)p * 5 + 2] = f2;
            smf4[(size_t)p * 5 + 3] = f3;
            smf4[(size_t)p * 5 + 4] = f4;
        }
        __syncthreads();

        const int wb = (c ? 12 : 0) + 3 * h;
        for (int w = wb; w < wb + 3; ++w) {
            const unsigned mw = JbT[(size_t)w * B_N + b];
            nob += __popc(mw);
            const int plb = w * 16 - (dbase >> 1);   // local pair base
            const float4* xp = Xt4 + (size_t)(w * 8) * B_N + b;
            #pragma unroll 2
            for (int g = 0; g < 8; ++g) {
                float4 xv = xp[(size_t)g * B_N];
                ACC_PAIR(plb + 2 * g,     g * 4,     xv.x, xv.y);
                ACC_PAIR(plb + 2 * g + 1, g * 4 + 2, xv.z, xv.w);
            }
        }
        if (c == 1 && h == 3) {  // tail word 24: bits 0..15 valid
            const unsigned mw = JbT[(size_t)24 * B_N + b];
            nob += __popc(mw);
            const int plb = 24 * 16 - 192;           // = 192
            const float4* xp = Xt4 + (size_t)(24 * 8) * B_N + b;
            #pragma unroll
            for (int g = 0; g < 4; ++g) {
                float4 xv = xp[(size_t)g * B_N];
                ACC_PAIR(plb + 2 * g,     g * 4,     xv.x, xv.y);
                ACC_PAIR(plb + 2 * g + 1, g * 4 + 2, xv.z, xv.w);
            }
        }
    }

    // horizontal add of packed halves
    float Pm[21], qv[6], quad, jld;
    #pragma unroll
    for (int t = 0; t < 21; ++t) Pm[t] = Pm2[t].x + Pm2[t].y;
    #pragma unroll
    for (int t = 0; t < 6; ++t) qv[t] = qv2[t].x + qv2[t].y;
    quad = quad2.x + quad2.y;
    jld  = jld2.x + jld2.y;

    __syncthreads();                     // records dead; slab aliases them
    float* red = smem;                   // 64 x 33 slab, conflict-free
    #define SLAB_WR do { float* o = &red[s * 33]; \
        _Pragma("unroll") for (int t = 0; t < 21; ++t) o[t] = Pm[t]; \
        _Pragma("unroll") for (int t = 0; t < 6; ++t) o[21 + t] = qv[t]; \
        o[27] = quad; o[28] = (float)nob; o[29] = jld; } while (0)
    #define SLAB_ADD do { const float* o = &red[s * 33]; \
        _Pragma("unroll") for (int t = 0; t < 21; ++t) Pm[t] += o[t]; \
        _Pragma("unroll") for (int t = 0; t < 6; ++t) qv[t] += o[21 + t]; \
        quad += o[27]; nob += (int)o[28]; jld += o[29]; } while (0)

    if (h == 1) SLAB_WR;
    __syncthreads();
    if (h == 0) SLAB_ADD;
    __syncthreads();
    if (h == 3) SLAB_WR;
    __syncthreads();
    if (h == 2) SLAB_ADD;
    __syncthreads();
    if (h == 2) SLAB_WR;
    __syncthreads();
    if (h == 0) {
        SLAB_ADD;
        float nobs = (float)nob;

        // P = I + sum
        Pm[0] += 1.f; Pm[2] += 1.f; Pm[5] += 1.f; Pm[9] += 1.f; Pm[14] += 1.f; Pm[20] += 1.f;

        float Lm[21], rd[6], sumlog;
        chol6(Pm, Lm, rd, &sumlog);
        float y[6];
        #pragma unroll
        for (int j = 0; j < 6; ++j) {
            float sv = qv[j];
            #pragma unroll
            for (int m = 0; m < j; ++m) sv -= Lm[IDX(j,m)] * y[m];
            y[j] = sv * rd[j];
        }
        float yy = 0.f;
        #pragma unroll
        for (int j = 0; j < 6; ++j) yy += y[j] * y[j];
        float logdet = 2.f * sumlog + jld;
        float ll = -0.5f * ((quad - yy) + logdet + nobs * LOG2PI_F);
        float score = ll + PI[k];

        scores[(size_t)k * B_N + b] = score;
        float* pq = Pq + (size_t)k * 27 * B_N + b;
        #pragma unroll
        for (int t = 0; t < 21; ++t) pq[(size_t)t * B_N] = Pm[t];
        #pragma unroll
        for (int t = 0; t < 6; ++t) pq[(size_t)(21 + t) * B_N] = qv[t];
    }
}

// ---------- KD: fused argmax + latent solve (wave 0 only) + output write ----------
__global__ __launch_bounds__(256) void k_outsel(
        const float* __restrict__ scores, const float* __restrict__ Pq,
        const float* __restrict__ A, const float* __restrict__ MU,
        const float* __restrict__ logD, float* __restrict__ out) {
    __shared__ float smz[6];
    __shared__ float sLz[21];
    __shared__ int sc;
    const int b = blockIdx.x;
    const int tid = threadIdx.x;

    if (tid < 64) {
        float best = scores[b];
        int bc = 0;
        for (int kk = 1; kk < K_N; ++kk) {
            float sv = scores[(size_t)kk * B_N + b];
            if (sv > best) { best = sv; bc = kk; }
        }

        float Pm[21], qv[6];
        const float* pq = Pq + (size_t)bc * 27 * B_N + b;
        #pragma unroll
        for (int t = 0; t < 21; ++t) Pm[t] = pq[(size_t)t * B_N];
        #pragma unroll
        for (int t = 0; t < 6; ++t) qv[t] = pq[(size_t)(21 + t) * B_N];

        float Lm[21], rd[6], dummy;
        chol6(Pm, Lm, rd, &dummy);

        float y[6];
        #pragma unroll
        for (int j = 0; j < 6; ++j) {
            float sv = qv[j];
            #pragma unroll
            for (int m = 0; m < j; ++m) sv -= Lm[IDX(j,m)] * y[m];
            y[j] = sv * rd[j];
        }
        float mz[6];
        #pragma unroll
        for (int ii = 5; ii >= 0; --ii) {
            float sv = y[ii];
            #pragma unroll
            for (int j = ii + 1; j < 6; ++j) sv -= Lm[IDX(j,ii)] * mz[j];
            mz[ii] = sv * rd[ii];
        }
        float Li[21];
        #pragma unroll
        for (int j = 0; j < 6; ++j) {
            Li[IDX(j,j)] = rd[j];
            #pragma unroll
            for (int i = j + 1; i < 6; ++i) {
                float sv = 0.f;
                #pragma unroll
                for (int m = j; m < i; ++m) sv += Lm[IDX(i,m)] * Li[IDX(m,j)];
                Li[IDX(i,j)] = -sv * rd[i];
            }
        }
        float cov[21];
        #pragma unroll
        for (int i = 0; i < 6; ++i) {
            #pragma unroll
            for (int j = 0; j <= i; ++j) {
                float sv = 0.f;
                #pragma unroll
                for (int m = i; m < 6; ++m) sv += Li[IDX(m,i)] * Li[IDX(m,j)];
                cov[IDX(i,j)] = sv;
            }
        }
        float Lz[21], rd2[6];
        chol6(cov, Lz, rd2, &dummy);

        if (tid == 0) {
            sc = bc;
            out[OUT_PW + b] = 1.0f;
            #pragma unroll
            for (int t = 0; t < 6; ++t) smz[t] = mz[t];
            #pragma unroll
            for (int t = 0; t < 21; ++t) sLz[t] = Lz[t];
        }
    }
    __syncthreads();
    const int c = sc;

    for (int d = tid; d < D_FT; d += 256) {
        const float2* ar2 = (const float2*)(A + ((size_t)c * D_FT + d) * 6);
        float2 p0 = ar2[0], p1 = ar2[1], p2 = ar2[2];
        float a[6] = { p0.x, p0.y, p1.x, p1.y, p2.x, p2.y };
        float mu = MU[(size_t)c * D_FT + d];
        float ld = logD[(size_t)c * D_FT + d];
        float m = mu;
        #pragma unroll
        for (int i = 0; i < 6; ++i) m += a[i] * smz[i];
        out[OUT_M + (size_t)b * D_FT + d] = m;
        out[OUT_D + (size_t)b * D_FT + d] = expf(ld);
        float o0, o1, o2, o3, o4, o5;
        o0 = a[0]*sLz[IDX(0,0)] + a[1]*sLz[IDX(1,0)] + a[2]*sLz[IDX(2,0)]
           + a[3]*sLz[IDX(3,0)] + a[4]*sLz[IDX(4,0)] + a[5]*sLz[IDX(5,0)];
        o1 = a[1]*sLz[IDX(1,1)] + a[2]*sLz[IDX(2,1)] + a[3]*sLz[IDX(3,1)]
           + a[4]*sLz[IDX(4,1)] + a[5]*sLz[IDX(5,1)];
        o2 = a[2]*sLz[IDX(2,2)] + a[3]*sLz[IDX(3,2)] + a[4]*sLz[IDX(4,2)] + a[5]*sLz[IDX(5,2)];
        o3 = a[3]*sLz[IDX(3,3)] + a[4]*sLz[IDX(4,3)] + a[5]*sLz[IDX(5,3)];
        o4 = a[4]*sLz[IDX(4,4)] + a[5]*sLz[IDX(5,4)];
        o5 = a[5]*sLz[IDX(5,5)];
        float2* ao2 = (float2*)(out + OUT_A + ((size_t)b * D_FT + d) * 6);
        float2 w0; w0.x = o0; w0.y = o1;
        float2 w1; w1.x = o2; w1.y = o3;
        float2 w2; w2.x = o4; w2.y = o5;
        ao2[0] = w0; ao2[1] = w1; ao2[2] = w2;
    }
}

extern "C" void kernel_launch(void* const* d_in, const int* in_sizes, int n_in,
                              void* d_out, int out_size, void* d_ws, size_t ws_size,
                              hipStream_t stream) {
    (void)in_sizes; (void)n_in; (void)out_size; (void)ws_size;
    const float* X    = (const float*)d_in[0];
    const int*   J    = (const int*)d_in[1];
    const float* MU   = (const float*)d_in[2];
    const float* A    = (const float*)d_in[3];
    const float* logD = (const float*)d_in[4];
    const float* PI   = (const float*)d_in[5];
    float* out = (float*)d_out;
    float* ws  = (float*)d_ws;

    float*    scores = ws + WS_SCORES;
    float*    Pq     = ws + WS_PQ;
    float4*   Xt4    = (float4*)(ws + WS_XT);
    unsigned* JbT    = (unsigned*)(ws + WS_JBT);

    k_prep<<<512, 1024, 0, stream>>>(X, J, Xt4, JbT);

    k_accum<<<32 * K_N, 256, 0, stream>>>(Xt4, JbT, A, MU, logD, PI, scores, Pq);

    k_outsel<<<B_N, 256, 0, stream>>>(scores, Pq, A, MU, logD, out);
}